// Round 4
// baseline (52.340 us; speedup 1.0000x reference)
//
#include <hip/hip_runtime.h>
#include <math.h>

#define Bb 128
#define Ee 256
#define Mm 64
#define Cc 5
#define NTOT (Bb*Mm*Ee)   // 2097152
#define BE  (Bb*Ee)       // 32768
#define EPS 1e-5f
#define L2E2 2.8853900817779268f   // 2*log2(e)

#if __has_builtin(__builtin_amdgcn_exp2f)
#define EXP2(x) __builtin_amdgcn_exp2f(x)
#else
#define EXP2(x) exp2f(x)
#endif
#define RCP(x) __builtin_amdgcn_rcpf(x)

// tanh with pre-scaled (by 2*log2e) weights: 1 - 2/(2^(x*w+b+h*u)+1).
__device__ __forceinline__ float tanh_step(float x, float w, float b, float u, float h) {
    float t = __builtin_fmaf(x, w, b);
    t = __builtin_fmaf(h, u, t);
    float r = RCP(EXP2(t) + 1.0f);
    return __builtin_fmaf(-2.0f, r, 1.0f);
}

// ---------------------------------------------------------------------------
// Kernel 1: per-sample scalar RNNs over T=4/8/16 + 1x3 conv fusion.
// Block = 256 threads = 256 consecutive samples. ALL global loads are dense
// (lane i loads chunk i, 1 KB/wave/instr); a1/a2 redistributed via LDS in
// [time][sample] layout (a2 rows padded to 257 -> conflict-free reads).
// fusion stored [m][b*E + e] so k_rnn2's per-step loads are coalesced.
// ---------------------------------------------------------------------------
__global__ __launch_bounds__(256) void k_rnn1(
    const float* __restrict__ a0, const float* __restrict__ a1,
    const float* __restrict__ a2,
    const float* __restrict__ wih, const float* __restrict__ whh,
    const float* __restrict__ bih, const float* __restrict__ bhh,
    const float* __restrict__ cw,  const float* __restrict__ cb,
    float* __restrict__ fusion)
{
    __shared__ float a1s[8 * 256];        // [k][s], k<8
    __shared__ float a2s[16 * 257];       // [k][s], padded row stride 257

    const int t   = threadIdx.x;
    const int blk = blockIdx.x;           // 8192 blocks x 256 samples
    const int base = blk << 8;            // first sample of block

    // a0: each thread's own sample is already a dense float4
    float4 x0 = ((const float4*)a0)[base + t];

    // a1: 512 chunks/block, 2 dense rounds; chunk c -> sample c>>1, half c&1
    #pragma unroll
    for (int r = 0; r < 2; ++r) {
        int c = (r << 8) + t;
        float4 v = ((const float4*)a1)[(size_t)(base << 1) + c];
        int s = c >> 1, row = (c & 1) << 2;
        a1s[(row + 0) * 256 + s] = v.x;
        a1s[(row + 1) * 256 + s] = v.y;
        a1s[(row + 2) * 256 + s] = v.z;
        a1s[(row + 3) * 256 + s] = v.w;
    }
    // a2: 1024 chunks/block, 4 dense rounds; chunk c -> sample c>>2, q c&3
    #pragma unroll
    for (int r = 0; r < 4; ++r) {
        int c = (r << 8) + t;
        float4 v = ((const float4*)a2)[(size_t)(base << 2) + c];
        int s = c >> 2, row = (c & 3) << 2;
        a2s[(row + 0) * 257 + s] = v.x;
        a2s[(row + 1) * 257 + s] = v.y;
        a2s[(row + 2) * 257 + s] = v.z;
        a2s[(row + 3) * 257 + s] = v.w;
    }

    // uniform pre-scaled constants (SGPRs)
    float w0 = wih[0] * L2E2, w1 = wih[1] * L2E2, w2 = wih[2] * L2E2;
    float u0 = whh[0] * L2E2, u1 = whh[1] * L2E2, u2 = whh[2] * L2E2;
    float b0 = (bih[0] + bhh[0]) * L2E2;
    float b1 = (bih[1] + bhh[1]) * L2E2;
    float b2 = (bih[2] + bhh[2]) * L2E2;
    float c0 = cw[0], c1 = cw[1], c2 = cw[2], cbias = cb[0];

    __syncthreads();

    // scale 0: T=4 (from registers)
    float h0 = tanh_step(x0.x, w0, b0, u0, 0.0f);
    h0 = tanh_step(x0.y, w0, b0, u0, h0);
    h0 = tanh_step(x0.z, w0, b0, u0, h0);
    h0 = tanh_step(x0.w, w0, b0, u0, h0);

    // scale 1: T=8 (LDS reads, conflict-free: lanes dense per row)
    float h1 = 0.0f;
    #pragma unroll
    for (int k = 0; k < 8; ++k)
        h1 = tanh_step(a1s[k * 256 + t], w1, b1, u1, h1);

    // scale 2: T=16
    float h2 = 0.0f;
    #pragma unroll
    for (int k = 0; k < 16; ++k)
        h2 = tanh_step(a2s[k * 257 + t], w2, b2, u2, h2);

    float f = h0 * c0 + h1 * c1 + h2 * c2 + cbias;

    // n = base + t; e = t, m = blk & 63, b = blk >> 6
    int m = blk & (Mm - 1);
    int b = blk >> 6;
    fusion[(m << 15) + (b << 8) + t] = f;   // [m][b*E+e]
}

// ---------------------------------------------------------------------------
// Kernel 2: second scalar RNN over m for each (b,e) lane.
// ---------------------------------------------------------------------------
__global__ __launch_bounds__(256) void k_rnn2(
    const float* __restrict__ fusion,
    const float* __restrict__ w, const float* __restrict__ u,
    const float* __restrict__ bi, const float* __restrict__ bh,
    float* __restrict__ feat)
{
    int j = blockIdx.x * blockDim.x + threadIdx.x;   // b*E + e
    float wv = w[0] * L2E2, uv = u[0] * L2E2, bb = (bi[0] + bh[0]) * L2E2;
    float h = 0.0f;
    #pragma unroll 16
    for (int m = 0; m < Mm; ++m) {
        float x = fusion[m * BE + j];
        h = tanh_step(x, wv, bb, uv, h);
    }
    feat[j] = h;
}

// ---------------------------------------------------------------------------
// Kernel 3: fused BatchNorm stats + norm + ReLU + (E->C) linear + softmax.
// One block per batch row; each block recomputes batch stats for its channels
// (feat is 128 KB, L2-hot; 16 MB aggregate ~ 0.5 us).
// ---------------------------------------------------------------------------
__global__ __launch_bounds__(256) void k_head(
    const float* __restrict__ feat,
    const float* __restrict__ gamma, const float* __restrict__ beta,
    const float* __restrict__ fw, const float* __restrict__ fb,
    float* __restrict__ out)
{
    int b = blockIdx.x;
    int e = threadIdx.x;

    // batch stats for channel e (biased variance)
    float s = 0.0f, s2 = 0.0f;
    #pragma unroll 8
    for (int bb = 0; bb < Bb; ++bb) {
        float v = feat[bb * Ee + e];
        s  += v;
        s2 += v * v;
    }
    float mean = s * (1.0f / Bb);
    float var  = s2 * (1.0f / Bb) - mean * mean;
    float a = gamma[e] * rsqrtf(var + EPS);
    float shift = beta[e] - mean * a;

    float v = feat[b * Ee + e] * a + shift;
    v = fmaxf(v, 0.0f);

    float p[Cc];
    #pragma unroll
    for (int c = 0; c < Cc; ++c) p[c] = v * fw[c * Ee + e];

    // wave(64)-level reduce, then cross-wave via LDS
    #pragma unroll
    for (int off = 32; off > 0; off >>= 1) {
        #pragma unroll
        for (int c = 0; c < Cc; ++c) p[c] += __shfl_down(p[c], off);
    }

    __shared__ float lds[4][Cc];
    int wave = e >> 6, lane = e & 63;
    if (lane == 0) {
        #pragma unroll
        for (int c = 0; c < Cc; ++c) lds[wave][c] = p[c];
    }
    __syncthreads();

    if (e == 0) {
        float lg[Cc];
        #pragma unroll
        for (int c = 0; c < Cc; ++c)
            lg[c] = lds[0][c] + lds[1][c] + lds[2][c] + lds[3][c] + fb[c];
        float mx = lg[0];
        #pragma unroll
        for (int c = 1; c < Cc; ++c) mx = fmaxf(mx, lg[c]);
        float se = 0.0f;
        #pragma unroll
        for (int c = 0; c < Cc; ++c) { lg[c] = EXP2((lg[c] - mx) * 1.4426950408889634f); se += lg[c]; }
        float inv = RCP(se);
        #pragma unroll
        for (int c = 0; c < Cc; ++c) out[b * Cc + c] = lg[c] * inv;
    }
}

extern "C" void kernel_launch(void* const* d_in, const int* in_sizes, int n_in,
                              void* d_out, int out_size, void* d_ws, size_t ws_size,
                              hipStream_t stream) {
    const float* a0       = (const float*)d_in[0];
    const float* a1       = (const float*)d_in[1];
    const float* a2       = (const float*)d_in[2];
    const float* rnn1_wih = (const float*)d_in[3];
    const float* rnn1_whh = (const float*)d_in[4];
    const float* rnn1_bih = (const float*)d_in[5];
    const float* rnn1_bhh = (const float*)d_in[6];
    const float* conv_w   = (const float*)d_in[7];
    const float* conv_b   = (const float*)d_in[8];
    const float* rnn2_wih = (const float*)d_in[9];
    const float* rnn2_whh = (const float*)d_in[10];
    const float* rnn2_bih = (const float*)d_in[11];
    const float* rnn2_bhh = (const float*)d_in[12];
    const float* gamma    = (const float*)d_in[13];
    const float* beta     = (const float*)d_in[14];
    const float* fnn_w    = (const float*)d_in[15];
    const float* fnn_b    = (const float*)d_in[16];

    float* out = (float*)d_out;

    // workspace layout
    char* ws = (char*)d_ws;
    float* fusion = (float*)ws;                            // M*BE floats = 8 MB
    float* feat   = (float*)(ws + (size_t)Mm * BE * 4);    // BE floats = 128 KB

    k_rnn1<<<NTOT / 256, 256, 0, stream>>>(a0, a1, a2,
        rnn1_wih, rnn1_whh, rnn1_bih, rnn1_bhh, conv_w, conv_b, fusion);
    k_rnn2<<<BE / 256, 256, 0, stream>>>(fusion,
        rnn2_wih, rnn2_whh, rnn2_bih, rnn2_bhh, feat);
    k_head<<<Bb, 256, 0, stream>>>(feat, gamma, beta, fnn_w, fnn_b, out);
}

// Round 5
// 50.807 us; speedup vs baseline: 1.0302x; 1.0302x over previous
//
#include <hip/hip_runtime.h>
#include <math.h>

#define Bb 128
#define Ee 256
#define Mm 64
#define Cc 5
#define NTOT (Bb*Mm*Ee)   // 2097152
#define BE  (Bb*Ee)       // 32768
#define EPS 1e-5f
#define L2E2 2.8853900817779268f   // 2*log2(e)

#if __has_builtin(__builtin_amdgcn_exp2f)
#define EXP2(x) __builtin_amdgcn_exp2f(x)
#else
#define EXP2(x) exp2f(x)
#endif
#define RCP(x) __builtin_amdgcn_rcpf(x)

// tanh with pre-scaled (by 2*log2e) weights: 1 - 2/(2^(x*w+b+h*u)+1).
// 4 regular VALU + 2 trans per step.
__device__ __forceinline__ float tanh_step(float x, float w, float b, float u, float h) {
    float t = __builtin_fmaf(x, w, b);
    t = __builtin_fmaf(h, u, t);
    float r = RCP(EXP2(t) + 1.0f);
    return __builtin_fmaf(-2.0f, r, 1.0f);
}

__device__ __forceinline__ unsigned short f32_to_bf16_rne(float f) {
    unsigned u = __float_as_uint(f);
    unsigned r = (u + 0x7fffu + ((u >> 16) & 1u)) >> 16;
    return (unsigned short)r;
}
__device__ __forceinline__ float bf16_to_f32(unsigned short s) {
    return __uint_as_float(((unsigned)s) << 16);
}

// ---------------------------------------------------------------------------
// Kernel 1: per-sample scalar RNNs over T=4/8/16 + 1x3 conv fusion.
// No LDS (round-4 showed staging is neutral: BW-wall, not access-pattern).
// 2 samples/thread (n, n+NTOT/2) -> 6 independent tanh chains for ILP.
// __launch_bounds__(256,8): 8 blocks/CU target, VGPR cap 64 (uses ~40).
// fusion stored bf16 [m][b*E+e] so k_rnn2's per-step loads are coalesced.
// ---------------------------------------------------------------------------
__global__ __launch_bounds__(256, 8) void k_rnn1(
    const float* __restrict__ a0, const float* __restrict__ a1,
    const float* __restrict__ a2,
    const float* __restrict__ wih, const float* __restrict__ whh,
    const float* __restrict__ bih, const float* __restrict__ bhh,
    const float* __restrict__ cw,  const float* __restrict__ cb,
    unsigned short* __restrict__ fusion)
{
    int t = blockIdx.x * blockDim.x + threadIdx.x;

    // uniform pre-scaled constants (SGPRs)
    float w0 = wih[0] * L2E2, w1 = wih[1] * L2E2, w2 = wih[2] * L2E2;
    float u0 = whh[0] * L2E2, u1 = whh[1] * L2E2, u2 = whh[2] * L2E2;
    float b0 = (bih[0] + bhh[0]) * L2E2;
    float b1 = (bih[1] + bhh[1]) * L2E2;
    float b2 = (bih[2] + bhh[2]) * L2E2;
    float c0 = cw[0], c1 = cw[1], c2 = cw[2], cbias = cb[0];

    #pragma unroll
    for (int s = 0; s < 2; ++s) {
        int n = t + s * (NTOT / 2);

        // scale 0: T=4 (16B/lane, dense)
        float4 x0 = ((const float4*)a0)[n];
        float h0 = tanh_step(x0.x, w0, b0, u0, 0.0f);
        h0 = tanh_step(x0.y, w0, b0, u0, h0);
        h0 = tanh_step(x0.z, w0, b0, u0, h0);
        h0 = tanh_step(x0.w, w0, b0, u0, h0);

        // scale 1: T=8
        float4 y0 = ((const float4*)a1)[2*n + 0];
        float4 y1 = ((const float4*)a1)[2*n + 1];
        float h1 = tanh_step(y0.x, w1, b1, u1, 0.0f);
        h1 = tanh_step(y0.y, w1, b1, u1, h1);
        h1 = tanh_step(y0.z, w1, b1, u1, h1);
        h1 = tanh_step(y0.w, w1, b1, u1, h1);
        h1 = tanh_step(y1.x, w1, b1, u1, h1);
        h1 = tanh_step(y1.y, w1, b1, u1, h1);
        h1 = tanh_step(y1.z, w1, b1, u1, h1);
        h1 = tanh_step(y1.w, w1, b1, u1, h1);

        // scale 2: T=16
        float h2 = 0.0f;
        #pragma unroll
        for (int q = 0; q < 4; ++q) {
            float4 z = ((const float4*)a2)[4*n + q];
            h2 = tanh_step(z.x, w2, b2, u2, h2);
            h2 = tanh_step(z.y, w2, b2, u2, h2);
            h2 = tanh_step(z.z, w2, b2, u2, h2);
            h2 = tanh_step(z.w, w2, b2, u2, h2);
        }

        float f = h0 * c0 + h1 * c1 + h2 * c2 + cbias;

        // n = (b<<14) | (m<<8) | e
        int e = n & (Ee - 1);
        int m = (n >> 8) & (Mm - 1);
        int b = n >> 14;
        fusion[(m << 15) + (b << 8) + e] = f32_to_bf16_rne(f);
    }
}

// ---------------------------------------------------------------------------
// Kernel 2: second scalar RNN over m for each (b,e) lane (bf16 input).
// ---------------------------------------------------------------------------
__global__ __launch_bounds__(256) void k_rnn2(
    const unsigned short* __restrict__ fusion,
    const float* __restrict__ w, const float* __restrict__ u,
    const float* __restrict__ bi, const float* __restrict__ bh,
    float* __restrict__ feat)
{
    int j = blockIdx.x * blockDim.x + threadIdx.x;   // b*E + e
    float wv = w[0] * L2E2, uv = u[0] * L2E2, bb = (bi[0] + bh[0]) * L2E2;
    float h = 0.0f;
    #pragma unroll 16
    for (int m = 0; m < Mm; ++m) {
        float x = bf16_to_f32(fusion[m * BE + j]);
        h = tanh_step(x, wv, bb, uv, h);
    }
    feat[j] = h;
}

// ---------------------------------------------------------------------------
// Kernel 3: fused BatchNorm stats + norm + ReLU + (E->C) linear + softmax.
// One block per batch row; stats recomputed per block (feat is L2-hot).
// ---------------------------------------------------------------------------
__global__ __launch_bounds__(256) void k_head(
    const float* __restrict__ feat,
    const float* __restrict__ gamma, const float* __restrict__ beta,
    const float* __restrict__ fw, const float* __restrict__ fb,
    float* __restrict__ out)
{
    int b = blockIdx.x;
    int e = threadIdx.x;

    float s = 0.0f, s2 = 0.0f;
    #pragma unroll 8
    for (int bb = 0; bb < Bb; ++bb) {
        float v = feat[bb * Ee + e];
        s  += v;
        s2 += v * v;
    }
    float mean = s * (1.0f / Bb);
    float var  = s2 * (1.0f / Bb) - mean * mean;
    float a = gamma[e] * rsqrtf(var + EPS);
    float shift = beta[e] - mean * a;

    float v = feat[b * Ee + e] * a + shift;
    v = fmaxf(v, 0.0f);

    float p[Cc];
    #pragma unroll
    for (int c = 0; c < Cc; ++c) p[c] = v * fw[c * Ee + e];

    #pragma unroll
    for (int off = 32; off > 0; off >>= 1) {
        #pragma unroll
        for (int c = 0; c < Cc; ++c) p[c] += __shfl_down(p[c], off);
    }

    __shared__ float lds[4][Cc];
    int wave = e >> 6, lane = e & 63;
    if (lane == 0) {
        #pragma unroll
        for (int c = 0; c < Cc; ++c) lds[wave][c] = p[c];
    }
    __syncthreads();

    if (e == 0) {
        float lg[Cc];
        #pragma unroll
        for (int c = 0; c < Cc; ++c)
            lg[c] = lds[0][c] + lds[1][c] + lds[2][c] + lds[3][c] + fb[c];
        float mx = lg[0];
        #pragma unroll
        for (int c = 1; c < Cc; ++c) mx = fmaxf(mx, lg[c]);
        float se = 0.0f;
        #pragma unroll
        for (int c = 0; c < Cc; ++c) { lg[c] = EXP2((lg[c] - mx) * 1.4426950408889634f); se += lg[c]; }
        float inv = RCP(se);
        #pragma unroll
        for (int c = 0; c < Cc; ++c) out[b * Cc + c] = lg[c] * inv;
    }
}

extern "C" void kernel_launch(void* const* d_in, const int* in_sizes, int n_in,
                              void* d_out, int out_size, void* d_ws, size_t ws_size,
                              hipStream_t stream) {
    const float* a0       = (const float*)d_in[0];
    const float* a1       = (const float*)d_in[1];
    const float* a2       = (const float*)d_in[2];
    const float* rnn1_wih = (const float*)d_in[3];
    const float* rnn1_whh = (const float*)d_in[4];
    const float* rnn1_bih = (const float*)d_in[5];
    const float* rnn1_bhh = (const float*)d_in[6];
    const float* conv_w   = (const float*)d_in[7];
    const float* conv_b   = (const float*)d_in[8];
    const float* rnn2_wih = (const float*)d_in[9];
    const float* rnn2_whh = (const float*)d_in[10];
    const float* rnn2_bih = (const float*)d_in[11];
    const float* rnn2_bhh = (const float*)d_in[12];
    const float* gamma    = (const float*)d_in[13];
    const float* beta     = (const float*)d_in[14];
    const float* fnn_w    = (const float*)d_in[15];
    const float* fnn_b    = (const float*)d_in[16];

    float* out = (float*)d_out;

    // workspace layout
    char* ws = (char*)d_ws;
    unsigned short* fusion = (unsigned short*)ws;              // M*BE bf16 = 4 MB
    float* feat = (float*)(ws + (size_t)Mm * BE * 2);          // BE floats = 128 KB

    k_rnn1<<<NTOT / 2 / 256, 256, 0, stream>>>(a0, a1, a2,
        rnn1_wih, rnn1_whh, rnn1_bih, rnn1_bhh, conv_w, conv_b, fusion);
    k_rnn2<<<BE / 256, 256, 0, stream>>>(fusion,
        rnn2_wih, rnn2_whh, rnn2_bih, rnn2_bhh, feat);
    k_head<<<Bb, 256, 0, stream>>>(feat, gamma, beta, fnn_w, fnn_b, out);
}